// Round 1
// 305.410 us; speedup vs baseline: 1.1324x; 1.1324x over previous
//
#include <hip/hip_runtime.h>

#define SEQ   2048
#define NHEAD 16
#define DKK   64
#define HID   1024

typedef __attribute__((ext_vector_type(8))) short bf16x8;
typedef __attribute__((ext_vector_type(4))) float f32x4;

__device__ __forceinline__ unsigned short f32_bf16(float f) {
    unsigned int u = __builtin_bit_cast(unsigned int, f);
    u += 0x7fffu + ((u >> 16) & 1u);
    return (unsigned short)(u >> 16);
}

__device__ __forceinline__ unsigned int pack_bf16x2(float a, float b) {
    return (unsigned int)f32_bf16(a) | ((unsigned int)f32_bf16(b) << 16);
}

// async global->LDS 16B copy (DMA, no VGPR round-trip)
__device__ __forceinline__ void glds16(const void* g, void* l) {
    __builtin_amdgcn_global_load_lds(
        (const __attribute__((address_space(1))) unsigned int*)g,
        (__attribute__((address_space(3))) unsigned int*)l, 16, 0, 0);
}

// ---------------------------------------------------------------------------
// Kernel A: fused prep — fp32->bf16 convert of all 7 tensors (dst regions are
// contiguous in ws in source order, so dst index == global index) + mask
// bit-pack, in a single launch (was 8 launches).
// ---------------------------------------------------------------------------
__global__ __launch_bounds__(256)
void prep_kernel(const float* __restrict__ q, const float* __restrict__ k,
                 const float* __restrict__ v,
                 const float* __restrict__ Wq, const float* __restrict__ Wk,
                 const float* __restrict__ Wv, const float* __restrict__ Wo,
                 const int* __restrict__ mask,
                 unsigned short* __restrict__ ws, unsigned long long* __restrict__ Mb)
{
    const int bid = blockIdx.x;
    if (bid < 16384) {
        int i = bid * 256 + threadIdx.x;            // float4 index
        const float* src; int off;
        if (i < 1048576)      { src = q;  off = i; }
        else if (i < 2097152) { src = k;  off = i - 1048576; }
        else if (i < 3145728) { src = v;  off = i - 2097152; }
        else if (i < 3407872) { src = Wq; off = i - 3145728; }
        else if (i < 3670016) { src = Wk; off = i - 3407872; }
        else if (i < 3932160) { src = Wv; off = i - 3670016; }
        else                  { src = Wo; off = i - 3932160; }
        float4 a = ((const float4*)src)[off];
        ((uint2*)ws)[i] = make_uint2(pack_bf16x2(a.x, a.y), pack_bf16x2(a.z, a.w));
    } else {
        int idx = (bid - 16384) * 256 + threadIdx.x;
        const int* src = mask + (size_t)idx * 64;
        unsigned long long wv = 0;
        #pragma unroll
        for (int i = 0; i < 16; ++i) {
            int4 m4 = *(const int4*)(src + i * 4);
            wv |= (unsigned long long)(m4.x != 0) << (i * 4 + 0);
            wv |= (unsigned long long)(m4.y != 0) << (i * 4 + 1);
            wv |= (unsigned long long)(m4.z != 0) << (i * 4 + 2);
            wv |= (unsigned long long)(m4.w != 0) << (i * 4 + 3);
        }
        Mb[idx] = wv;
    }
}

// ---------------------------------------------------------------------------
// Kernel 1: QKV projections, m97-structure (unchanged except: Q output is
// pre-scaled by 0.125*log2(e) so attn's exp2 needs no multiply).
// ---------------------------------------------------------------------------
__global__ __launch_bounds__(256, 2)
void proj_kernel(const unsigned short* __restrict__ xq, const unsigned short* __restrict__ xk,
                 const unsigned short* __restrict__ xv,
                 const unsigned short* __restrict__ Wqb, const unsigned short* __restrict__ Wkb,
                 const unsigned short* __restrict__ Wvb,
                 const float* __restrict__ bq_, const float* __restrict__ bk_,
                 const float* __restrict__ bv_,
                 unsigned short* __restrict__ Qh, unsigned short* __restrict__ Kh,
                 unsigned short* __restrict__ Vt)
{
    const int z = blockIdx.z;
    const unsigned short* X; const unsigned short* W; const float* bias;
    if (z == 0)      { X = xq; W = Wqb; bias = bq_; }
    else if (z == 1) { X = xk; W = Wkb; bias = bk_; }
    else             { X = xv; W = Wvb; bias = bv_; }

    const int m0 = blockIdx.x * 128;
    const int n0 = blockIdx.y * 128;
    const int tid  = threadIdx.x;
    const int lane = tid & 63, wid = tid >> 6;
    const int wm = (wid >> 1) * 64, wn = (wid & 1) * 64;
    const int l15 = lane & 15, quad = lane >> 4;

    __shared__ __align__(16) unsigned short As[128 * 32];
    __shared__ __align__(16) unsigned short Bs[128 * 32];

    const int r0 = tid >> 2, cg = tid & 3;
    const unsigned short* gA = X + (size_t)(m0 + r0) * HID + ((cg ^ (r0 & 3)) * 8);
    const unsigned short* gB = W + (size_t)(n0 + r0) * HID + ((cg ^ (r0 & 3)) * 8);
    unsigned short* lA0 = &As[tid * 8];
    unsigned short* lA1 = &As[(tid + 256) * 8];
    unsigned short* lB0 = &Bs[tid * 8];
    unsigned short* lB1 = &Bs[(tid + 256) * 8];

    const int cgsel = (quad ^ (l15 & 3)) * 8;

    f32x4 acc[4][4];
    #pragma unroll
    for (int i = 0; i < 4; ++i)
        #pragma unroll
        for (int j = 0; j < 4; ++j)
            acc[i][j] = f32x4{0.f, 0.f, 0.f, 0.f};

    for (int k0 = 0; k0 < HID; k0 += 32) {
        glds16(gA + k0, lA0);
        glds16(gA + (size_t)64 * HID + k0, lA1);
        glds16(gB + k0, lB0);
        glds16(gB + (size_t)64 * HID + k0, lB1);
        __syncthreads();

        bf16x8 af[4], bfr[4];
        #pragma unroll
        for (int mi = 0; mi < 4; ++mi)
            af[mi] = *(const bf16x8*)&As[(wm + mi * 16 + l15) * 32 + cgsel];
        #pragma unroll
        for (int ni = 0; ni < 4; ++ni)
            bfr[ni] = *(const bf16x8*)&Bs[(wn + ni * 16 + l15) * 32 + cgsel];
        #pragma unroll
        for (int mi = 0; mi < 4; ++mi)
            #pragma unroll
            for (int ni = 0; ni < 4; ++ni)
                acc[mi][ni] = __builtin_amdgcn_mfma_f32_16x16x32_bf16(
                    af[mi], bfr[ni], acc[mi][ni], 0, 0, 0);
        __syncthreads();
    }

    const float QSCALE = 0.18033688f;   // 0.125 * log2(e)
    #pragma unroll
    for (int mi = 0; mi < 4; ++mi) {
        #pragma unroll
        for (int ni = 0; ni < 4; ++ni) {
            int n = n0 + wn + ni * 16 + l15;
            float bv = bias[n];
            int hh = n >> 6, d = n & 63;
            #pragma unroll
            for (int r = 0; r < 4; ++r) {
                int m = m0 + wm + mi * 16 + quad * 4 + r;
                int bb = m >> 11, s = m & 2047;
                float val = acc[mi][ni][r] + bv;
                if (z == 0)
                    Qh[((size_t)(bb * NHEAD + hh) * SEQ + s) * DKK + d] = f32_bf16(val * QSCALE);
                else if (z == 1)
                    Kh[((size_t)(bb * NHEAD + hh) * SEQ + s) * DKK + d] = f32_bf16(val);
                else
                    Vt[((size_t)(bb * NHEAD + hh) * DKK + d) * SEQ + s] = f32_bf16(val);
            }
        }
    }
}

// ---------------------------------------------------------------------------
// Kernel 2: flash attention, restructured.
//  - sequential k-tiles (no split-K); all 4 waves share one K/V tile.
//  - K/V staged via global_load_lds into XOR-swizzled, double-buffered LDS
//    (swizzle applied on the per-lane GLOBAL source address; LDS dest linear).
//  - wave w owns q-rows w*16..w*16+15: o_acc is 16 VGPRs, no cross-wave
//    reduction epilogue (ones-MFMA row-sum leaves L in every lane).
//  - P buffer per wave 16x64, chunk-XOR swizzled on both store and read.
//  - one __syncthreads per k-tile; its vmcnt drain completes the prefetch
//    issued at the top of the iteration.
//  LDS = 2*8K (K) + 2*8K (V) + 4*2K (P) = 40960 B -> 4 blocks/CU.
// ---------------------------------------------------------------------------
__global__ __launch_bounds__(256, 4)
void attn_kernel(const unsigned short* __restrict__ Qh, const unsigned short* __restrict__ Kh,
                 const unsigned short* __restrict__ Vt,
                 const unsigned long long* __restrict__ Mb,
                 unsigned short* __restrict__ Om)
{
    const int qt = blockIdx.x;       // 0..31
    const int h  = blockIdx.y;
    const int b  = blockIdx.z;
    const int tid  = threadIdx.x;
    const int lane = tid & 63, w = tid >> 6;
    const int l15 = lane & 15, quad = lane >> 4;
    const int q0 = qt * 64;

    const size_t hoff = (size_t)(b * NHEAD + h) * SEQ * DKK;
    const unsigned short* Qp = Qh + hoff;
    const unsigned short* Kp = Kh + hoff;
    const unsigned short* Vp = Vt + hoff;   // [d][s]

    __shared__ __align__(16) unsigned short Ks[2][64 * 64];
    __shared__ __align__(16) unsigned short Vs[2][64 * 64];
    __shared__ __align__(16) unsigned short Ps[4][16 * 64];

    // staging: chunk c (16B) for c = tid, tid+256; row = c>>3, sub = c&7;
    // LDS slot (row,sub) holds global chunk (row, sub ^ (row&7)).
    const int sr0 = tid >> 3, ss0 = tid & 7;
    const int sr1 = sr0 + 32;
    const unsigned short* Kg0 = Kp + sr0 * DKK + ((ss0 ^ (sr0 & 7)) * 8);
    const unsigned short* Kg1 = Kp + sr1 * DKK + ((ss0 ^ (sr1 & 7)) * 8);
    const unsigned short* Vg0 = Vp + (size_t)sr0 * SEQ + ((ss0 ^ (sr0 & 7)) * 8);
    const unsigned short* Vg1 = Vp + (size_t)sr1 * SEQ + ((ss0 ^ (sr1 & 7)) * 8);

    // fragment-read swizzled chunk offsets (row&7 == l15&7 for all frag rows)
    const int swz0 = ((0 * 4 + quad) ^ (l15 & 7)) * 8;
    const int swz1 = ((1 * 4 + quad) ^ (l15 & 7)) * 8;

    // issue first tile before anything else so the DMA flies under Q loads
    glds16(Kg0, &Ks[0][tid * 8]);
    glds16(Kg1, &Ks[0][2048 + tid * 8]);
    glds16(Vg0, &Vs[0][tid * 8]);
    glds16(Vg1, &Vs[0][2048 + tid * 8]);

    // Q fragments: wave w owns rows q0 + w*16 .. +15 (Q pre-scaled in proj)
    bf16x8 qf[2];
    #pragma unroll
    for (int kc = 0; kc < 2; ++kc)
        qf[kc] = *(const bf16x8*)(Qp + (size_t)(q0 + w * 16 + l15) * DKK + kc * 32 + quad * 8);

    bf16x8 onesf;
    #pragma unroll
    for (int i = 0; i < 8; ++i) onesf[i] = (short)0x3F80;

    f32x4 o_acc[4];
    f32x4 l_acc = f32x4{0.f, 0.f, 0.f, 0.f};
    #pragma unroll
    for (int nd = 0; nd < 4; ++nd) o_acc[nd] = f32x4{0.f, 0.f, 0.f, 0.f};

    const unsigned long long* Mrow =
        Mb + ((size_t)b * SEQ + q0 + w * 16 + quad * 4) * (SEQ / 64);

    __syncthreads();                       // tile 0 staged

    for (int kt = 0; kt < SEQ / 64; ++kt) {
        const int cur = kt & 1;
        if (kt < SEQ / 64 - 1) {           // prefetch next tile into other buf
            const int nb = cur ^ 1;
            glds16(Kg0 + (kt + 1) * 64 * DKK, &Ks[nb][tid * 8]);
            glds16(Kg1 + (kt + 1) * 64 * DKK, &Ks[nb][2048 + tid * 8]);
            glds16(Vg0 + (kt + 1) * 64,       &Vs[nb][tid * 8]);
            glds16(Vg1 + (kt + 1) * 64,       &Vs[nb][2048 + tid * 8]);
        }

        unsigned long long mw[4];
        #pragma unroll
        for (int r = 0; r < 4; ++r)
            mw[r] = Mrow[(size_t)r * (SEQ / 64) + kt] >> l15;

        // QK^T
        f32x4 s[4];
        #pragma unroll
        for (int ni = 0; ni < 4; ++ni) s[ni] = f32x4{0.f, 0.f, 0.f, 0.f};
        {
            bf16x8 kb[4];
            #pragma unroll
            for (int ni = 0; ni < 4; ++ni)
                kb[ni] = *(const bf16x8*)&Ks[cur][(ni * 16 + l15) * 64 + swz0];
            #pragma unroll
            for (int ni = 0; ni < 4; ++ni)
                s[ni] = __builtin_amdgcn_mfma_f32_16x16x32_bf16(qf[0], kb[ni], s[ni], 0, 0, 0);
            #pragma unroll
            for (int ni = 0; ni < 4; ++ni)
                kb[ni] = *(const bf16x8*)&Ks[cur][(ni * 16 + l15) * 64 + swz1];
            #pragma unroll
            for (int ni = 0; ni < 4; ++ni)
                s[ni] = __builtin_amdgcn_mfma_f32_16x16x32_bf16(qf[1], kb[ni], s[ni], 0, 0, 0);
        }

        // softmax numerator -> P (bf16), chunk-swizzled store
        #pragma unroll
        for (int r = 0; r < 4; ++r) {
            const int prow = quad * 4 + r;
            unsigned short* pp = &Ps[w][prow * 64];
            const int rx = prow & 7;
            #pragma unroll
            for (int ni = 0; ni < 4; ++ni) {
                float e = exp2f(s[ni][r]);
                float p = ((mw[r] >> (ni * 16)) & 1) ? e : 1.0f;
                const int col = ni * 16 + l15;
                pp[(((col >> 3) ^ rx) * 8) + (col & 7)] = f32_bf16(p);
            }
        }

        // PV + row-sum (ones trick). P read row = l15, same swizzle family.
        {
            bf16x8 pa = *(const bf16x8*)&Ps[w][l15 * 64 + swz0];
            bf16x8 vb[4];
            #pragma unroll
            for (int nd = 0; nd < 4; ++nd)
                vb[nd] = *(const bf16x8*)&Vs[cur][(nd * 16 + l15) * 64 + swz0];
            l_acc = __builtin_amdgcn_mfma_f32_16x16x32_bf16(pa, onesf, l_acc, 0, 0, 0);
            #pragma unroll
            for (int nd = 0; nd < 4; ++nd)
                o_acc[nd] = __builtin_amdgcn_mfma_f32_16x16x32_bf16(pa, vb[nd], o_acc[nd], 0, 0, 0);

            pa = *(const bf16x8*)&Ps[w][l15 * 64 + swz1];
            #pragma unroll
            for (int nd = 0; nd < 4; ++nd)
                vb[nd] = *(const bf16x8*)&Vs[cur][(nd * 16 + l15) * 64 + swz1];
            l_acc = __builtin_amdgcn_mfma_f32_16x16x32_bf16(pa, onesf, l_acc, 0, 0, 0);
            #pragma unroll
            for (int nd = 0; nd < 4; ++nd)
                o_acc[nd] = __builtin_amdgcn_mfma_f32_16x16x32_bf16(pa, vb[nd], o_acc[nd], 0, 0, 0);
        }

        __syncthreads();   // reads of cur done; prefetch (vmcnt) drained
    }

    // epilogue: every lane already holds L for its rows in l_acc
    #pragma unroll
    for (int r = 0; r < 4; ++r) {
        float rinv = 1.0f / l_acc[r];
        int row = q0 + w * 16 + quad * 4 + r;
        #pragma unroll
        for (int nd = 0; nd < 4; ++nd)
            Om[((size_t)b * SEQ + row) * HID + h * DKK + nd * 16 + l15] =
                f32_bf16(o_acc[nd][r] * rinv);
    }
}

// ---------------------------------------------------------------------------
// Kernel 3: out = Om @ Wo^T + bo (fp32 out), m97-structure (unchanged).
// ---------------------------------------------------------------------------
__global__ __launch_bounds__(256, 2)
void outproj_kernel(const unsigned short* __restrict__ Om, const unsigned short* __restrict__ Wob,
                    const float* __restrict__ bo_, float* __restrict__ out)
{
    const int m0 = blockIdx.x * 128;
    const int n0 = blockIdx.y * 128;
    const int tid  = threadIdx.x;
    const int lane = tid & 63, wid = tid >> 6;
    const int wm = (wid >> 1) * 64, wn = (wid & 1) * 64;
    const int l15 = lane & 15, quad = lane >> 4;

    __shared__ __align__(16) unsigned short As[128 * 32];
    __shared__ __align__(16) unsigned short Bs[128 * 32];

    const int r0 = tid >> 2, cg = tid & 3;
    const unsigned short* gA = Om + (size_t)(m0 + r0) * HID + ((cg ^ (r0 & 3)) * 8);
    const unsigned short* gB = Wob + (size_t)(n0 + r0) * HID + ((cg ^ (r0 & 3)) * 8);
    unsigned short* lA0 = &As[tid * 8];
    unsigned short* lA1 = &As[(tid + 256) * 8];
    unsigned short* lB0 = &Bs[tid * 8];
    unsigned short* lB1 = &Bs[(tid + 256) * 8];
    const int cgsel = (quad ^ (l15 & 3)) * 8;

    f32x4 acc[4][4];
    #pragma unroll
    for (int i = 0; i < 4; ++i)
        #pragma unroll
        for (int j = 0; j < 4; ++j)
            acc[i][j] = f32x4{0.f, 0.f, 0.f, 0.f};

    for (int k0 = 0; k0 < HID; k0 += 32) {
        glds16(gA + k0, lA0);
        glds16(gA + (size_t)64 * HID + k0, lA1);
        glds16(gB + k0, lB0);
        glds16(gB + (size_t)64 * HID + k0, lB1);
        __syncthreads();

        bf16x8 af[4], bfr[4];
        #pragma unroll
        for (int mi = 0; mi < 4; ++mi)
            af[mi] = *(const bf16x8*)&As[(wm + mi * 16 + l15) * 32 + cgsel];
        #pragma unroll
        for (int ni = 0; ni < 4; ++ni)
            bfr[ni] = *(const bf16x8*)&Bs[(wn + ni * 16 + l15) * 32 + cgsel];
        #pragma unroll
        for (int mi = 0; mi < 4; ++mi)
            #pragma unroll
            for (int ni = 0; ni < 4; ++ni)
                acc[mi][ni] = __builtin_amdgcn_mfma_f32_16x16x32_bf16(
                    af[mi], bfr[ni], acc[mi][ni], 0, 0, 0);
        __syncthreads();
    }

    #pragma unroll
    for (int mi = 0; mi < 4; ++mi) {
        #pragma unroll
        for (int ni = 0; ni < 4; ++ni) {
            int n = n0 + wn + ni * 16 + l15;
            float bv = bo_[n];
            #pragma unroll
            for (int r = 0; r < 4; ++r) {
                int m = m0 + wm + mi * 16 + quad * 4 + r;
                out[(size_t)m * HID + n] = acc[mi][ni][r] + bv;
            }
        }
    }
}

// ---------------------------------------------------------------------------
extern "C" void kernel_launch(void* const* d_in, const int* in_sizes, int n_in,
                              void* d_out, int out_size, void* d_ws, size_t ws_size,
                              hipStream_t stream) {
    const float* q    = (const float*)d_in[0];
    const float* k    = (const float*)d_in[1];
    const float* v    = (const float*)d_in[2];
    const int*   mask = (const int*)  d_in[3];
    const float* Wq   = (const float*)d_in[4];
    const float* bq   = (const float*)d_in[5];
    const float* Wk   = (const float*)d_in[6];
    const float* bk   = (const float*)d_in[7];
    const float* Wv   = (const float*)d_in[8];
    const float* bv   = (const float*)d_in[9];
    const float* Wo   = (const float*)d_in[10];
    const float* bo   = (const float*)d_in[11];
    float* out = (float*)d_out;

    // workspace layout (bf16 element offsets):
    unsigned short* ws  = (unsigned short*)d_ws;
    unsigned short* qb  = ws;                  // 4194304 elems (B*S*H)
    unsigned short* kbx = ws + 4194304;
    unsigned short* vbx = ws + 8388608;
    unsigned short* Wqb = ws + 12582912;       // 1048576 elems each
    unsigned short* Wkb = ws + 13631488;
    unsigned short* Wvb = ws + 14680064;
    unsigned short* Wob = ws + 15728640;
    unsigned short* Qh  = ws + 16777216;
    unsigned short* Kh  = ws + 20971520;
    unsigned short* Vt  = ws + 25165824;
    unsigned short* Om  = ws;                  // alias qb (dead after proj)
    unsigned long long* Mb = (unsigned long long*)(ws + 29360128);  // 1 MB

    // 16384 cvt blocks (4194304 float4 total) + 512 mask-pack blocks
    prep_kernel<<<dim3(16896), 256, 0, stream>>>(q, k, v, Wq, Wk, Wv, Wo, mask, ws, Mb);

    proj_kernel<<<dim3(32, 8, 3), 256, 0, stream>>>(qb, kbx, vbx, Wqb, Wkb, Wvb,
                                                    bq, bk, bv, Qh, Kh, Vt);
    attn_kernel<<<dim3(32, NHEAD, 2), 256, 0, stream>>>(Qh, Kh, Vt, Mb, Om);
    outproj_kernel<<<dim3(32, 8, 1), 256, 0, stream>>>(Om, Wob, bo, out);
}

// Round 2
// 292.238 us; speedup vs baseline: 1.1835x; 1.0451x over previous
//
#include <hip/hip_runtime.h>

#define SEQ   2048
#define NHEAD 16
#define DKK   64
#define HID   1024

typedef __attribute__((ext_vector_type(8))) short bf16x8;
typedef __attribute__((ext_vector_type(4))) float f32x4;

__device__ __forceinline__ unsigned short f32_bf16(float f) {
    unsigned int u = __builtin_bit_cast(unsigned int, f);
    u += 0x7fffu + ((u >> 16) & 1u);
    return (unsigned short)(u >> 16);
}

__device__ __forceinline__ unsigned int pack_bf16x2(float a, float b) {
    return (unsigned int)f32_bf16(a) | ((unsigned int)f32_bf16(b) << 16);
}

// raw v_exp_f32 (2^x). Scores bounded (|x| < ~45), no range reduction needed.
__device__ __forceinline__ float fast_exp2(float x) {
    float r;
    asm("v_exp_f32 %0, %1" : "=v"(r) : "v"(x));
    return r;
}

// async global->LDS 16B copy (DMA, no VGPR round-trip)
__device__ __forceinline__ void glds16(const void* g, void* l) {
    __builtin_amdgcn_global_load_lds(
        (const __attribute__((address_space(1))) unsigned int*)g,
        (__attribute__((address_space(3))) unsigned int*)l, 16, 0, 0);
}

// ---------------------------------------------------------------------------
// Kernel A: fused prep — fp32->bf16 convert of all 7 tensors + mask bit-pack.
// ---------------------------------------------------------------------------
__global__ __launch_bounds__(256)
void prep_kernel(const float* __restrict__ q, const float* __restrict__ k,
                 const float* __restrict__ v,
                 const float* __restrict__ Wq, const float* __restrict__ Wk,
                 const float* __restrict__ Wv, const float* __restrict__ Wo,
                 const int* __restrict__ mask,
                 unsigned short* __restrict__ ws, unsigned long long* __restrict__ Mb)
{
    const int bid = blockIdx.x;
    if (bid < 16384) {
        int i = bid * 256 + threadIdx.x;            // float4 index
        const float* src; int off;
        if (i < 1048576)      { src = q;  off = i; }
        else if (i < 2097152) { src = k;  off = i - 1048576; }
        else if (i < 3145728) { src = v;  off = i - 2097152; }
        else if (i < 3407872) { src = Wq; off = i - 3145728; }
        else if (i < 3670016) { src = Wk; off = i - 3407872; }
        else if (i < 3932160) { src = Wv; off = i - 3670016; }
        else                  { src = Wo; off = i - 3932160; }
        float4 a = ((const float4*)src)[off];
        ((uint2*)ws)[i] = make_uint2(pack_bf16x2(a.x, a.y), pack_bf16x2(a.z, a.w));
    } else {
        int idx = (bid - 16384) * 256 + threadIdx.x;
        const int* src = mask + (size_t)idx * 64;
        unsigned long long wv = 0;
        #pragma unroll
        for (int i = 0; i < 16; ++i) {
            int4 m4 = *(const int4*)(src + i * 4);
            wv |= (unsigned long long)(m4.x != 0) << (i * 4 + 0);
            wv |= (unsigned long long)(m4.y != 0) << (i * 4 + 1);
            wv |= (unsigned long long)(m4.z != 0) << (i * 4 + 2);
            wv |= (unsigned long long)(m4.w != 0) << (i * 4 + 3);
        }
        Mb[idx] = wv;
    }
}

// ---------------------------------------------------------------------------
// Kernel 1: QKV projections, m97-structure (Q pre-scaled by 0.125*log2(e)).
// ---------------------------------------------------------------------------
__global__ __launch_bounds__(256, 2)
void proj_kernel(const unsigned short* __restrict__ xq, const unsigned short* __restrict__ xk,
                 const unsigned short* __restrict__ xv,
                 const unsigned short* __restrict__ Wqb, const unsigned short* __restrict__ Wkb,
                 const unsigned short* __restrict__ Wvb,
                 const float* __restrict__ bq_, const float* __restrict__ bk_,
                 const float* __restrict__ bv_,
                 unsigned short* __restrict__ Qh, unsigned short* __restrict__ Kh,
                 unsigned short* __restrict__ Vt)
{
    const int z = blockIdx.z;
    const unsigned short* X; const unsigned short* W; const float* bias;
    if (z == 0)      { X = xq; W = Wqb; bias = bq_; }
    else if (z == 1) { X = xk; W = Wkb; bias = bk_; }
    else             { X = xv; W = Wvb; bias = bv_; }

    const int m0 = blockIdx.x * 128;
    const int n0 = blockIdx.y * 128;
    const int tid  = threadIdx.x;
    const int lane = tid & 63, wid = tid >> 6;
    const int wm = (wid >> 1) * 64, wn = (wid & 1) * 64;
    const int l15 = lane & 15, quad = lane >> 4;

    __shared__ __align__(16) unsigned short As[128 * 32];
    __shared__ __align__(16) unsigned short Bs[128 * 32];

    const int r0 = tid >> 2, cg = tid & 3;
    const unsigned short* gA = X + (size_t)(m0 + r0) * HID + ((cg ^ (r0 & 3)) * 8);
    const unsigned short* gB = W + (size_t)(n0 + r0) * HID + ((cg ^ (r0 & 3)) * 8);
    unsigned short* lA0 = &As[tid * 8];
    unsigned short* lA1 = &As[(tid + 256) * 8];
    unsigned short* lB0 = &Bs[tid * 8];
    unsigned short* lB1 = &Bs[(tid + 256) * 8];

    const int cgsel = (quad ^ (l15 & 3)) * 8;

    f32x4 acc[4][4];
    #pragma unroll
    for (int i = 0; i < 4; ++i)
        #pragma unroll
        for (int j = 0; j < 4; ++j)
            acc[i][j] = f32x4{0.f, 0.f, 0.f, 0.f};

    for (int k0 = 0; k0 < HID; k0 += 32) {
        glds16(gA + k0, lA0);
        glds16(gA + (size_t)64 * HID + k0, lA1);
        glds16(gB + k0, lB0);
        glds16(gB + (size_t)64 * HID + k0, lB1);
        __syncthreads();

        bf16x8 af[4], bfr[4];
        #pragma unroll
        for (int mi = 0; mi < 4; ++mi)
            af[mi] = *(const bf16x8*)&As[(wm + mi * 16 + l15) * 32 + cgsel];
        #pragma unroll
        for (int ni = 0; ni < 4; ++ni)
            bfr[ni] = *(const bf16x8*)&Bs[(wn + ni * 16 + l15) * 32 + cgsel];
        #pragma unroll
        for (int mi = 0; mi < 4; ++mi)
            #pragma unroll
            for (int ni = 0; ni < 4; ++ni)
                acc[mi][ni] = __builtin_amdgcn_mfma_f32_16x16x32_bf16(
                    af[mi], bfr[ni], acc[mi][ni], 0, 0, 0);
        __syncthreads();
    }

    const float QSCALE = 0.18033688f;   // 0.125 * log2(e)
    #pragma unroll
    for (int mi = 0; mi < 4; ++mi) {
        #pragma unroll
        for (int ni = 0; ni < 4; ++ni) {
            int n = n0 + wn + ni * 16 + l15;
            float bv = bias[n];
            int hh = n >> 6, d = n & 63;
            #pragma unroll
            for (int r = 0; r < 4; ++r) {
                int m = m0 + wm + mi * 16 + quad * 4 + r;
                int bb = m >> 11, s = m & 2047;
                float val = acc[mi][ni][r] + bv;
                if (z == 0)
                    Qh[((size_t)(bb * NHEAD + hh) * SEQ + s) * DKK + d] = f32_bf16(val * QSCALE);
                else if (z == 1)
                    Kh[((size_t)(bb * NHEAD + hh) * SEQ + s) * DKK + d] = f32_bf16(val);
                else
                    Vt[((size_t)(bb * NHEAD + hh) * DKK + d) * SEQ + s] = f32_bf16(val);
            }
        }
    }
}

// ---------------------------------------------------------------------------
// Kernel 2: flash attention, swapped-QK^T form.
//  - mfma(K,Q) puts S^T in regs: lane holds S[q=l15][k=ni*16+quad*4+r] — the
//    4 values per ni are k-CONTIGUOUS, so the P-store packs into one
//    ds_write_b64 per ni (4 stores/k-tile, was 16 scalar b16 stores), with
//    all addresses precomputed outside the loop.
//  - mask: ONE u64 word per k-tile per lane (lane's own q-row), was 4.
//  - raw v_exp_f32 instead of exp2f libcall.
//  - P swizzle: 8B chunk c at row q stored at c ^ (q & 14): write lanes with
//    equal chunk spread over banks; 16B PV reads stay aligned (XOR value even)
//    and land conflict-free.
//  - K/V staging, double-buffer, PV, ones-row-sum, epilogue: as round 1.
//  LDS = 2*8K (K) + 2*8K (V) + 4*2K (P) = 40960 B -> 4 blocks/CU.
// ---------------------------------------------------------------------------
__global__ __launch_bounds__(256, 4)
void attn_kernel(const unsigned short* __restrict__ Qh, const unsigned short* __restrict__ Kh,
                 const unsigned short* __restrict__ Vt,
                 const unsigned long long* __restrict__ Mb,
                 unsigned short* __restrict__ Om)
{
    const int qt = blockIdx.x;       // 0..31
    const int h  = blockIdx.y;
    const int b  = blockIdx.z;
    const int tid  = threadIdx.x;
    const int lane = tid & 63, w = tid >> 6;
    const int l15 = lane & 15, quad = lane >> 4;
    const int q0 = qt * 64;

    const size_t hoff = (size_t)(b * NHEAD + h) * SEQ * DKK;
    const unsigned short* Qp = Qh + hoff;
    const unsigned short* Kp = Kh + hoff;
    const unsigned short* Vp = Vt + hoff;   // [d][s]

    __shared__ __align__(16) unsigned short Ks[2][64 * 64];
    __shared__ __align__(16) unsigned short Vs[2][64 * 64];
    __shared__ __align__(16) unsigned short Ps[4][16 * 64];

    // staging: chunk c (16B) for c = tid, tid+256; row = c>>3, sub = c&7;
    // LDS slot (row,sub) holds global chunk (row, sub ^ (row&7)).
    const int sr0 = tid >> 3, ss0 = tid & 7;
    const int sr1 = sr0 + 32;
    const unsigned short* Kg0 = Kp + sr0 * DKK + ((ss0 ^ (sr0 & 7)) * 8);
    const unsigned short* Kg1 = Kp + sr1 * DKK + ((ss0 ^ (sr1 & 7)) * 8);
    const unsigned short* Vg0 = Vp + (size_t)sr0 * SEQ + ((ss0 ^ (sr0 & 7)) * 8);
    const unsigned short* Vg1 = Vp + (size_t)sr1 * SEQ + ((ss0 ^ (sr1 & 7)) * 8);

    // K/V fragment-read swizzled chunk offsets (row&7 == l15&7 for frag rows)
    const int swz0 = ((0 * 4 + quad) ^ (l15 & 7)) * 8;
    const int swz1 = ((1 * 4 + quad) ^ (l15 & 7)) * 8;

    // P-buffer addresses (ushort offsets), precomputed once.
    // write: logical 8B chunk c = ni*4+quad of row l15 -> phys c ^ (l15&14)
    // read (PV A-frag, kc): 16B block at even chunk e = kc*8+quad*2
    const int xsw = l15 & 14;
    int wadr[4];
    #pragma unroll
    for (int ni = 0; ni < 4; ++ni)
        wadr[ni] = l15 * 64 + (((ni * 4 + quad) ^ xsw) * 4);
    const int padr0 = l15 * 64 + (((quad * 2) ^ xsw) * 4);
    const int padr1 = l15 * 64 + (((8 + quad * 2) ^ xsw) * 4);

    // issue first tile before anything else so the DMA flies under Q loads
    glds16(Kg0, &Ks[0][tid * 8]);
    glds16(Kg1, &Ks[0][2048 + tid * 8]);
    glds16(Vg0, &Vs[0][tid * 8]);
    glds16(Vg1, &Vs[0][2048 + tid * 8]);

    // Q fragments: wave w owns rows q0 + w*16 .. +15 (Q pre-scaled in proj)
    bf16x8 qf[2];
    #pragma unroll
    for (int kc = 0; kc < 2; ++kc)
        qf[kc] = *(const bf16x8*)(Qp + (size_t)(q0 + w * 16 + l15) * DKK + kc * 32 + quad * 8);

    bf16x8 onesf;
    #pragma unroll
    for (int i = 0; i < 8; ++i) onesf[i] = (short)0x3F80;

    f32x4 o_acc[4];
    f32x4 l_acc = f32x4{0.f, 0.f, 0.f, 0.f};
    #pragma unroll
    for (int nd = 0; nd < 4; ++nd) o_acc[nd] = f32x4{0.f, 0.f, 0.f, 0.f};

    // one mask word per k-tile: row = lane's q-row, bits = k offsets 0..63
    const unsigned long long* Mrow =
        Mb + ((size_t)b * SEQ + q0 + w * 16 + l15) * (SEQ / 64);

    __syncthreads();                       // tile 0 staged

    for (int kt = 0; kt < SEQ / 64; ++kt) {
        const int cur = kt & 1;
        if (kt < SEQ / 64 - 1) {           // prefetch next tile into other buf
            const int nb = cur ^ 1;
            glds16(Kg0 + (kt + 1) * 64 * DKK, &Ks[nb][tid * 8]);
            glds16(Kg1 + (kt + 1) * 64 * DKK, &Ks[nb][2048 + tid * 8]);
            glds16(Vg0 + (kt + 1) * 64,       &Vs[nb][tid * 8]);
            glds16(Vg1 + (kt + 1) * 64,       &Vs[nb][2048 + tid * 8]);
        }

        const unsigned long long mwq = Mrow[kt] >> (quad * 4);

        // QK^T, swapped operands: st[ni] row=(k in frag ni), col=(q=l15)
        f32x4 st[4];
        #pragma unroll
        for (int ni = 0; ni < 4; ++ni) st[ni] = f32x4{0.f, 0.f, 0.f, 0.f};
        {
            bf16x8 kb[4];
            #pragma unroll
            for (int ni = 0; ni < 4; ++ni)
                kb[ni] = *(const bf16x8*)&Ks[cur][(ni * 16 + l15) * 64 + swz0];
            __builtin_amdgcn_s_setprio(1);
            #pragma unroll
            for (int ni = 0; ni < 4; ++ni)
                st[ni] = __builtin_amdgcn_mfma_f32_16x16x32_bf16(kb[ni], qf[0], st[ni], 0, 0, 0);
            __builtin_amdgcn_s_setprio(0);
            #pragma unroll
            for (int ni = 0; ni < 4; ++ni)
                kb[ni] = *(const bf16x8*)&Ks[cur][(ni * 16 + l15) * 64 + swz1];
            __builtin_amdgcn_s_setprio(1);
            #pragma unroll
            for (int ni = 0; ni < 4; ++ni)
                st[ni] = __builtin_amdgcn_mfma_f32_16x16x32_bf16(kb[ni], qf[1], st[ni], 0, 0, 0);
            __builtin_amdgcn_s_setprio(0);
        }

        // softmax numerator -> P (bf16), one packed b64 store per ni
        #pragma unroll
        for (int ni = 0; ni < 4; ++ni) {
            const unsigned int b4 = (unsigned int)(mwq >> (ni * 16)) & 0xFu;
            float p0 = (b4 & 1u) ? fast_exp2(st[ni][0]) : 1.0f;
            float p1 = (b4 & 2u) ? fast_exp2(st[ni][1]) : 1.0f;
            float p2 = (b4 & 4u) ? fast_exp2(st[ni][2]) : 1.0f;
            float p3 = (b4 & 8u) ? fast_exp2(st[ni][3]) : 1.0f;
            *(uint2*)&Ps[w][wadr[ni]] = make_uint2(pack_bf16x2(p0, p1), pack_bf16x2(p2, p3));
        }

        // PV + row-sum (ones trick)
        {
            bf16x8 pa = *(const bf16x8*)&Ps[w][padr0];
            bf16x8 vb[4];
            #pragma unroll
            for (int nd = 0; nd < 4; ++nd)
                vb[nd] = *(const bf16x8*)&Vs[cur][(nd * 16 + l15) * 64 + swz0];
            __builtin_amdgcn_s_setprio(1);
            l_acc = __builtin_amdgcn_mfma_f32_16x16x32_bf16(pa, onesf, l_acc, 0, 0, 0);
            #pragma unroll
            for (int nd = 0; nd < 4; ++nd)
                o_acc[nd] = __builtin_amdgcn_mfma_f32_16x16x32_bf16(pa, vb[nd], o_acc[nd], 0, 0, 0);
            __builtin_amdgcn_s_setprio(0);

            pa = *(const bf16x8*)&Ps[w][padr1];
            #pragma unroll
            for (int nd = 0; nd < 4; ++nd)
                vb[nd] = *(const bf16x8*)&Vs[cur][(nd * 16 + l15) * 64 + swz1];
            __builtin_amdgcn_s_setprio(1);
            l_acc = __builtin_amdgcn_mfma_f32_16x16x32_bf16(pa, onesf, l_acc, 0, 0, 0);
            #pragma unroll
            for (int nd = 0; nd < 4; ++nd)
                o_acc[nd] = __builtin_amdgcn_mfma_f32_16x16x32_bf16(pa, vb[nd], o_acc[nd], 0, 0, 0);
            __builtin_amdgcn_s_setprio(0);
        }

        __syncthreads();   // reads of cur done; prefetch (vmcnt) drained
    }

    // epilogue: lane holds rows quad*4+r (D-row = P-row index), col d = l15
    #pragma unroll
    for (int r = 0; r < 4; ++r) {
        float rinv = 1.0f / l_acc[r];
        int row = q0 + w * 16 + quad * 4 + r;
        #pragma unroll
        for (int nd = 0; nd < 4; ++nd)
            Om[((size_t)b * SEQ + row) * HID + h * DKK + nd * 16 + l15] =
                f32_bf16(o_acc[nd][r] * rinv);
    }
}

// ---------------------------------------------------------------------------
// Kernel 3: out = Om @ Wo^T + bo (fp32 out), m97-structure (unchanged).
// ---------------------------------------------------------------------------
__global__ __launch_bounds__(256, 2)
void outproj_kernel(const unsigned short* __restrict__ Om, const unsigned short* __restrict__ Wob,
                    const float* __restrict__ bo_, float* __restrict__ out)
{
    const int m0 = blockIdx.x * 128;
    const int n0 = blockIdx.y * 128;
    const int tid  = threadIdx.x;
    const int lane = tid & 63, wid = tid >> 6;
    const int wm = (wid >> 1) * 64, wn = (wid & 1) * 64;
    const int l15 = lane & 15, quad = lane >> 4;

    __shared__ __align__(16) unsigned short As[128 * 32];
    __shared__ __align__(16) unsigned short Bs[128 * 32];

    const int r0 = tid >> 2, cg = tid & 3;
    const unsigned short* gA = Om + (size_t)(m0 + r0) * HID + ((cg ^ (r0 & 3)) * 8);
    const unsigned short* gB = Wob + (size_t)(n0 + r0) * HID + ((cg ^ (r0 & 3)) * 8);
    unsigned short* lA0 = &As[tid * 8];
    unsigned short* lA1 = &As[(tid + 256) * 8];
    unsigned short* lB0 = &Bs[tid * 8];
    unsigned short* lB1 = &Bs[(tid + 256) * 8];
    const int cgsel = (quad ^ (l15 & 3)) * 8;

    f32x4 acc[4][4];
    #pragma unroll
    for (int i = 0; i < 4; ++i)
        #pragma unroll
        for (int j = 0; j < 4; ++j)
            acc[i][j] = f32x4{0.f, 0.f, 0.f, 0.f};

    for (int k0 = 0; k0 < HID; k0 += 32) {
        glds16(gA + k0, lA0);
        glds16(gA + (size_t)64 * HID + k0, lA1);
        glds16(gB + k0, lB0);
        glds16(gB + (size_t)64 * HID + k0, lB1);
        __syncthreads();

        bf16x8 af[4], bfr[4];
        #pragma unroll
        for (int mi = 0; mi < 4; ++mi)
            af[mi] = *(const bf16x8*)&As[(wm + mi * 16 + l15) * 32 + cgsel];
        #pragma unroll
        for (int ni = 0; ni < 4; ++ni)
            bfr[ni] = *(const bf16x8*)&Bs[(wn + ni * 16 + l15) * 32 + cgsel];
        #pragma unroll
        for (int mi = 0; mi < 4; ++mi)
            #pragma unroll
            for (int ni = 0; ni < 4; ++ni)
                acc[mi][ni] = __builtin_amdgcn_mfma_f32_16x16x32_bf16(
                    af[mi], bfr[ni], acc[mi][ni], 0, 0, 0);
        __syncthreads();
    }

    #pragma unroll
    for (int mi = 0; mi < 4; ++mi) {
        #pragma unroll
        for (int ni = 0; ni < 4; ++ni) {
            int n = n0 + wn + ni * 16 + l15;
            float bv = bo_[n];
            #pragma unroll
            for (int r = 0; r < 4; ++r) {
                int m = m0 + wm + mi * 16 + quad * 4 + r;
                out[(size_t)m * HID + n] = acc[mi][ni][r] + bv;
            }
        }
    }
}

// ---------------------------------------------------------------------------
extern "C" void kernel_launch(void* const* d_in, const int* in_sizes, int n_in,
                              void* d_out, int out_size, void* d_ws, size_t ws_size,
                              hipStream_t stream) {
    const float* q    = (const float*)d_in[0];
    const float* k    = (const float*)d_in[1];
    const float* v    = (const float*)d_in[2];
    const int*   mask = (const int*)  d_in[3];
    const float* Wq   = (const float*)d_in[4];
    const float* bq   = (const float*)d_in[5];
    const float* Wk   = (const float*)d_in[6];
    const float* bk   = (const float*)d_in[7];
    const float* Wv   = (const float*)d_in[8];
    const float* bv   = (const float*)d_in[9];
    const float* Wo   = (const float*)d_in[10];
    const float* bo   = (const float*)d_in[11];
    float* out = (float*)d_out;

    // workspace layout (bf16 element offsets):
    unsigned short* ws  = (unsigned short*)d_ws;
    unsigned short* qb  = ws;                  // 4194304 elems (B*S*H)
    unsigned short* kbx = ws + 4194304;
    unsigned short* vbx = ws + 8388608;
    unsigned short* Wqb = ws + 12582912;       // 1048576 elems each
    unsigned short* Wkb = ws + 13631488;
    unsigned short* Wvb = ws + 14680064;
    unsigned short* Wob = ws + 15728640;
    unsigned short* Qh  = ws + 16777216;
    unsigned short* Kh  = ws + 20971520;
    unsigned short* Vt  = ws + 25165824;
    unsigned short* Om  = ws;                  // alias qb (dead after proj)
    unsigned long long* Mb = (unsigned long long*)(ws + 29360128);  // 1 MB

    // 16384 cvt blocks (4194304 float4 total) + 512 mask-pack blocks
    prep_kernel<<<dim3(16896), 256, 0, stream>>>(q, k, v, Wq, Wk, Wv, Wo, mask, ws, Mb);

    proj_kernel<<<dim3(32, 8, 3), 256, 0, stream>>>(qb, kbx, vbx, Wqb, Wkb, Wvb,
                                                    bq, bk, bv, Qh, Kh, Vt);
    attn_kernel<<<dim3(32, NHEAD, 2), 256, 0, stream>>>(Qh, Kh, Vt, Mb, Om);
    outproj_kernel<<<dim3(32, 8, 1), 256, 0, stream>>>(Om, Wob, bo, out);
}

// Round 4
// 279.340 us; speedup vs baseline: 1.2381x; 1.0462x over previous
//
#include <hip/hip_runtime.h>

#define SEQ   2048
#define NHEAD 16
#define DKK   64
#define HID   1024

typedef __attribute__((ext_vector_type(8))) short bf16x8;
typedef __attribute__((ext_vector_type(4))) float f32x4;

__device__ __forceinline__ unsigned short f32_bf16(float f) {
    unsigned int u = __builtin_bit_cast(unsigned int, f);
    u += 0x7fffu + ((u >> 16) & 1u);
    return (unsigned short)(u >> 16);
}

// one-instruction packed f32x2 -> bf16x2 (RNE), per T12 recipe
__device__ __forceinline__ unsigned int cvt_pk_bf16(float lo, float hi) {
    unsigned int r;
    asm("v_cvt_pk_bf16_f32 %0, %1, %2" : "=v"(r) : "v"(lo), "v"(hi));
    return r;
}

// raw v_exp_f32 (2^x). Scores bounded (|x| < ~45), no range reduction needed.
__device__ __forceinline__ float fast_exp2(float x) {
    float r;
    asm("v_exp_f32 %0, %1" : "=v"(r) : "v"(x));
    return r;
}

// async global->LDS 16B copy (DMA, no VGPR round-trip)
__device__ __forceinline__ void glds16(const void* g, void* l) {
    __builtin_amdgcn_global_load_lds(
        (const __attribute__((address_space(1))) unsigned int*)g,
        (__attribute__((address_space(3))) unsigned int*)l, 16, 0, 0);
}

// ---------------------------------------------------------------------------
// Kernel A: fused prep — fp32->bf16 convert of all 7 tensors + mask bit-pack.
// ---------------------------------------------------------------------------
__global__ __launch_bounds__(256)
void prep_kernel(const float* __restrict__ q, const float* __restrict__ k,
                 const float* __restrict__ v,
                 const float* __restrict__ Wq, const float* __restrict__ Wk,
                 const float* __restrict__ Wv, const float* __restrict__ Wo,
                 const int* __restrict__ mask,
                 unsigned short* __restrict__ ws, unsigned long long* __restrict__ Mb)
{
    const int bid = blockIdx.x;
    if (bid < 16384) {
        int i = bid * 256 + threadIdx.x;            // float4 index
        const float* src; int off;
        if (i < 1048576)      { src = q;  off = i; }
        else if (i < 2097152) { src = k;  off = i - 1048576; }
        else if (i < 3145728) { src = v;  off = i - 2097152; }
        else if (i < 3407872) { src = Wq; off = i - 3145728; }
        else if (i < 3670016) { src = Wk; off = i - 3407872; }
        else if (i < 3932160) { src = Wv; off = i - 3670016; }
        else                  { src = Wo; off = i - 3932160; }
        float4 a = ((const float4*)src)[off];
        ((uint2*)ws)[i] = make_uint2(cvt_pk_bf16(a.x, a.y), cvt_pk_bf16(a.z, a.w));
    } else {
        int idx = (bid - 16384) * 256 + threadIdx.x;
        const int* src = mask + (size_t)idx * 64;
        unsigned long long wv = 0;
        #pragma unroll
        for (int i = 0; i < 16; ++i) {
            int4 m4 = *(const int4*)(src + i * 4);
            wv |= (unsigned long long)(m4.x != 0) << (i * 4 + 0);
            wv |= (unsigned long long)(m4.y != 0) << (i * 4 + 1);
            wv |= (unsigned long long)(m4.z != 0) << (i * 4 + 2);
            wv |= (unsigned long long)(m4.w != 0) << (i * 4 + 3);
        }
        Mb[idx] = wv;
    }
}

// ---------------------------------------------------------------------------
// Kernel 1: QKV projections.  Double-buffered LDS, ONE barrier per K-step
// (attn-style: prefetch at top, barrier at bottom drains it).  Q pre-scaled
// by 0.125*log2(e).  z=2 (V) writes COALESCED [b,h,s,d] into scratch Vh;
// a separate transpose kernel builds Vt[d][s].
// ---------------------------------------------------------------------------
__global__ __launch_bounds__(256, 2)
void proj_kernel(const unsigned short* __restrict__ xq, const unsigned short* __restrict__ xk,
                 const unsigned short* __restrict__ xv,
                 const unsigned short* __restrict__ Wqb, const unsigned short* __restrict__ Wkb,
                 const unsigned short* __restrict__ Wvb,
                 const float* __restrict__ bq_, const float* __restrict__ bk_,
                 const float* __restrict__ bv_,
                 unsigned short* __restrict__ Qh, unsigned short* __restrict__ Kh,
                 unsigned short* __restrict__ Vh)
{
    const int z = blockIdx.z;
    const unsigned short* X; const unsigned short* W; const float* bias;
    if (z == 0)      { X = xq; W = Wqb; bias = bq_; }
    else if (z == 1) { X = xk; W = Wkb; bias = bk_; }
    else             { X = xv; W = Wvb; bias = bv_; }

    const int m0 = blockIdx.x * 128;
    const int n0 = blockIdx.y * 128;
    const int tid  = threadIdx.x;
    const int lane = tid & 63, wid = tid >> 6;
    const int wm = (wid >> 1) * 64, wn = (wid & 1) * 64;
    const int l15 = lane & 15, quad = lane >> 4;

    __shared__ __align__(16) unsigned short As[2][128 * 32];   // 2 x 8 KB
    __shared__ __align__(16) unsigned short Bs[2][128 * 32];

    const int r0 = tid >> 2, cg = tid & 3;
    const unsigned short* gA = X + (size_t)(m0 + r0) * HID + ((cg ^ (r0 & 3)) * 8);
    const unsigned short* gB = W + (size_t)(n0 + r0) * HID + ((cg ^ (r0 & 3)) * 8);

    const int cgsel = (quad ^ (l15 & 3)) * 8;

    f32x4 acc[4][4];
    #pragma unroll
    for (int i = 0; i < 4; ++i)
        #pragma unroll
        for (int j = 0; j < 4; ++j)
            acc[i][j] = f32x4{0.f, 0.f, 0.f, 0.f};

    // prologue: stage k0=0 into buf 0
    glds16(gA, &As[0][tid * 8]);
    glds16(gA + (size_t)64 * HID, &As[0][(tid + 256) * 8]);
    glds16(gB, &Bs[0][tid * 8]);
    glds16(gB + (size_t)64 * HID, &Bs[0][(tid + 256) * 8]);
    __syncthreads();

    for (int k0 = 0; k0 < HID; k0 += 32) {
        const int cur = (k0 >> 5) & 1;
        if (k0 + 32 < HID) {                       // prefetch next K-step
            const int nb = cur ^ 1;
            glds16(gA + k0 + 32, &As[nb][tid * 8]);
            glds16(gA + (size_t)64 * HID + k0 + 32, &As[nb][(tid + 256) * 8]);
            glds16(gB + k0 + 32, &Bs[nb][tid * 8]);
            glds16(gB + (size_t)64 * HID + k0 + 32, &Bs[nb][(tid + 256) * 8]);
        }

        bf16x8 af[4], bfr[4];
        #pragma unroll
        for (int mi = 0; mi < 4; ++mi)
            af[mi] = *(const bf16x8*)&As[cur][(wm + mi * 16 + l15) * 32 + cgsel];
        #pragma unroll
        for (int ni = 0; ni < 4; ++ni)
            bfr[ni] = *(const bf16x8*)&Bs[cur][(wn + ni * 16 + l15) * 32 + cgsel];
        __builtin_amdgcn_s_setprio(1);
        #pragma unroll
        for (int mi = 0; mi < 4; ++mi)
            #pragma unroll
            for (int ni = 0; ni < 4; ++ni)
                acc[mi][ni] = __builtin_amdgcn_mfma_f32_16x16x32_bf16(
                    af[mi], bfr[ni], acc[mi][ni], 0, 0, 0);
        __builtin_amdgcn_s_setprio(0);
        __syncthreads();                           // reads done + prefetch drained
    }

    const float QSCALE = 0.18033688f;   // 0.125 * log2(e)
    #pragma unroll
    for (int mi = 0; mi < 4; ++mi) {
        #pragma unroll
        for (int ni = 0; ni < 4; ++ni) {
            int n = n0 + wn + ni * 16 + l15;
            float bv = bias[n];
            int hh = n >> 6, d = n & 63;
            #pragma unroll
            for (int r = 0; r < 4; ++r) {
                int m = m0 + wm + mi * 16 + quad * 4 + r;
                int bb = m >> 11, s = m & 2047;
                float val = acc[mi][ni][r] + bv;
                if (z == 0)
                    Qh[((size_t)(bb * NHEAD + hh) * SEQ + s) * DKK + d] = f32_bf16(val * QSCALE);
                else if (z == 1)
                    Kh[((size_t)(bb * NHEAD + hh) * SEQ + s) * DKK + d] = f32_bf16(val);
                else
                    Vh[((size_t)(bb * NHEAD + hh) * SEQ + s) * DKK + d] = f32_bf16(val);
            }
        }
    }
}

// ---------------------------------------------------------------------------
// Kernel 1b: Vh[b,h,s,d] -> Vt[b,h,d,s] transpose, 64x64 LDS tiles.
// Tile = 64 s-rows x 64 d = 64 rows x 8 chunks of 16B.  FIXED from round 3:
// write phase indexes s = i>>3, ch = i&7 (was i>>2/i&3: only half the d-range
// staged and s ran to 127 -> LDS out-of-bounds -> corrupted V).
// Swizzle: chunk ch of row s stored at phys chunk ch^(s>>3); read phase
// fetches u32 w4 of chunk g at phys g^(s>>3) — consistent.
// ---------------------------------------------------------------------------
__global__ __launch_bounds__(256)
void vtrans_kernel(const unsigned short* __restrict__ Vh, unsigned short* __restrict__ Vt)
{
    __shared__ unsigned int T[64 * 32];
    const int bh = blockIdx.y;
    const int s0 = blockIdx.x * 64;
    const int tid = threadIdx.x;
    const unsigned short* src = Vh + ((size_t)bh * SEQ + s0) * DKK;
    unsigned short* dst = Vt + (size_t)bh * DKK * SEQ + s0;

    #pragma unroll
    for (int j = 0; j < 2; ++j) {
        int i = tid + j * 256;
        int s = i >> 3, ch = i & 7;                // 16B chunk: d = ch*8..+7
        uint4 d4 = *(const uint4*)(src + (size_t)s * DKK + ch * 8);
        *(uint4*)&T[s * 32 + 4 * (ch ^ (s >> 3))] = d4;
    }
    __syncthreads();
    #pragma unroll
    for (int j = 0; j < 2; ++j) {
        int i = tid + j * 256;
        int d = i >> 3, sb = (i & 7) * 8;          // 8 consecutive s at row d
        int d2 = d >> 1, hi = d & 1;
        int g = d2 >> 2, w4 = d2 & 3;
        unsigned int r[8];
        #pragma unroll
        for (int kk = 0; kk < 8; ++kk) {
            int s = sb + kk;
            r[kk] = T[s * 32 + 4 * (g ^ (s >> 3)) + w4];
        }
        uint4 ov;
        if (hi) {
            ov.x = (r[0] >> 16) | (r[1] & 0xffff0000u);
            ov.y = (r[2] >> 16) | (r[3] & 0xffff0000u);
            ov.z = (r[4] >> 16) | (r[5] & 0xffff0000u);
            ov.w = (r[6] >> 16) | (r[7] & 0xffff0000u);
        } else {
            ov.x = (r[0] & 0xffffu) | (r[1] << 16);
            ov.y = (r[2] & 0xffffu) | (r[3] << 16);
            ov.z = (r[4] & 0xffffu) | (r[5] << 16);
            ov.w = (r[6] & 0xffffu) | (r[7] << 16);
        }
        *(uint4*)(dst + (size_t)d * SEQ + sb) = ov;
    }
}

// ---------------------------------------------------------------------------
// Kernel 2: flash attention, swapped-QK^T form (round-2 structure).
// P-pack uses v_cvt_pk_bf16_f32 (1 instr vs ~9 manual ops).
// ---------------------------------------------------------------------------
__global__ __launch_bounds__(256, 4)
void attn_kernel(const unsigned short* __restrict__ Qh, const unsigned short* __restrict__ Kh,
                 const unsigned short* __restrict__ Vt,
                 const unsigned long long* __restrict__ Mb,
                 unsigned short* __restrict__ Om)
{
    const int qt = blockIdx.x;       // 0..31
    const int h  = blockIdx.y;
    const int b  = blockIdx.z;
    const int tid  = threadIdx.x;
    const int lane = tid & 63, w = tid >> 6;
    const int l15 = lane & 15, quad = lane >> 4;
    const int q0 = qt * 64;

    const size_t hoff = (size_t)(b * NHEAD + h) * SEQ * DKK;
    const unsigned short* Qp = Qh + hoff;
    const unsigned short* Kp = Kh + hoff;
    const unsigned short* Vp = Vt + hoff;   // [d][s]

    __shared__ __align__(16) unsigned short Ks[2][64 * 64];
    __shared__ __align__(16) unsigned short Vs[2][64 * 64];
    __shared__ __align__(16) unsigned short Ps[4][16 * 64];

    const int sr0 = tid >> 3, ss0 = tid & 7;
    const int sr1 = sr0 + 32;
    const unsigned short* Kg0 = Kp + sr0 * DKK + ((ss0 ^ (sr0 & 7)) * 8);
    const unsigned short* Kg1 = Kp + sr1 * DKK + ((ss0 ^ (sr1 & 7)) * 8);
    const unsigned short* Vg0 = Vp + (size_t)sr0 * SEQ + ((ss0 ^ (sr0 & 7)) * 8);
    const unsigned short* Vg1 = Vp + (size_t)sr1 * SEQ + ((ss0 ^ (sr1 & 7)) * 8);

    const int swz0 = ((0 * 4 + quad) ^ (l15 & 7)) * 8;
    const int swz1 = ((1 * 4 + quad) ^ (l15 & 7)) * 8;

    const int xsw = l15 & 14;
    int wadr[4];
    #pragma unroll
    for (int ni = 0; ni < 4; ++ni)
        wadr[ni] = l15 * 64 + (((ni * 4 + quad) ^ xsw) * 4);
    const int padr0 = l15 * 64 + (((quad * 2) ^ xsw) * 4);
    const int padr1 = l15 * 64 + (((8 + quad * 2) ^ xsw) * 4);

    glds16(Kg0, &Ks[0][tid * 8]);
    glds16(Kg1, &Ks[0][2048 + tid * 8]);
    glds16(Vg0, &Vs[0][tid * 8]);
    glds16(Vg1, &Vs[0][2048 + tid * 8]);

    bf16x8 qf[2];
    #pragma unroll
    for (int kc = 0; kc < 2; ++kc)
        qf[kc] = *(const bf16x8*)(Qp + (size_t)(q0 + w * 16 + l15) * DKK + kc * 32 + quad * 8);

    bf16x8 onesf;
    #pragma unroll
    for (int i = 0; i < 8; ++i) onesf[i] = (short)0x3F80;

    f32x4 o_acc[4];
    f32x4 l_acc = f32x4{0.f, 0.f, 0.f, 0.f};
    #pragma unroll
    for (int nd = 0; nd < 4; ++nd) o_acc[nd] = f32x4{0.f, 0.f, 0.f, 0.f};

    const unsigned long long* Mrow =
        Mb + ((size_t)b * SEQ + q0 + w * 16 + l15) * (SEQ / 64);

    __syncthreads();                       // tile 0 staged

    for (int kt = 0; kt < SEQ / 64; ++kt) {
        const int cur = kt & 1;
        if (kt < SEQ / 64 - 1) {
            const int nb = cur ^ 1;
            glds16(Kg0 + (kt + 1) * 64 * DKK, &Ks[nb][tid * 8]);
            glds16(Kg1 + (kt + 1) * 64 * DKK, &Ks[nb][2048 + tid * 8]);
            glds16(Vg0 + (kt + 1) * 64,       &Vs[nb][tid * 8]);
            glds16(Vg1 + (kt + 1) * 64,       &Vs[nb][2048 + tid * 8]);
        }

        const unsigned long long mwq = Mrow[kt] >> (quad * 4);

        f32x4 st[4];
        #pragma unroll
        for (int ni = 0; ni < 4; ++ni) st[ni] = f32x4{0.f, 0.f, 0.f, 0.f};
        {
            bf16x8 kb[4];
            #pragma unroll
            for (int ni = 0; ni < 4; ++ni)
                kb[ni] = *(const bf16x8*)&Ks[cur][(ni * 16 + l15) * 64 + swz0];
            __builtin_amdgcn_s_setprio(1);
            #pragma unroll
            for (int ni = 0; ni < 4; ++ni)
                st[ni] = __builtin_amdgcn_mfma_f32_16x16x32_bf16(kb[ni], qf[0], st[ni], 0, 0, 0);
            __builtin_amdgcn_s_setprio(0);
            #pragma unroll
            for (int ni = 0; ni < 4; ++ni)
                kb[ni] = *(const bf16x8*)&Ks[cur][(ni * 16 + l15) * 64 + swz1];
            __builtin_amdgcn_s_setprio(1);
            #pragma unroll
            for (int ni = 0; ni < 4; ++ni)
                st[ni] = __builtin_amdgcn_mfma_f32_16x16x32_bf16(kb[ni], qf[1], st[ni], 0, 0, 0);
            __builtin_amdgcn_s_setprio(0);
        }

        // softmax numerator -> P (bf16), packed via v_cvt_pk_bf16_f32
        #pragma unroll
        for (int ni = 0; ni < 4; ++ni) {
            const unsigned int b4 = (unsigned int)(mwq >> (ni * 16)) & 0xFu;
            float p0 = (b4 & 1u) ? fast_exp2(st[ni][0]) : 1.0f;
            float p1 = (b4 & 2u) ? fast_exp2(st[ni][1]) : 1.0f;
            float p2 = (b4 & 4u) ? fast_exp2(st[ni][2]) : 1.0f;
            float p3 = (b4 & 8u) ? fast_exp2(st[ni][3]) : 1.0f;
            *(uint2*)&Ps[w][wadr[ni]] = make_uint2(cvt_pk_bf16(p0, p1), cvt_pk_bf16(p2, p3));
        }

        // PV + row-sum (ones trick)
        {
            bf16x8 pa = *(const bf16x8*)&Ps[w][padr0];
            bf16x8 vb[4];
            #pragma unroll
            for (int nd = 0; nd < 4; ++nd)
                vb[nd] = *(const bf16x8*)&Vs[cur][(nd * 16 + l15) * 64 + swz0];
            __builtin_amdgcn_s_setprio(1);
            l_acc = __builtin_amdgcn_mfma_f32_16x16x32_bf16(pa, onesf, l_acc, 0, 0, 0);
            #pragma unroll
            for (int nd = 0; nd < 4; ++nd)
                o_acc[nd] = __builtin_amdgcn_mfma_f32_16x16x32_bf16(pa, vb[nd], o_acc[nd], 0, 0, 0);
            __builtin_amdgcn_s_setprio(0);

            pa = *(const bf16x8*)&Ps[w][padr1];
            #pragma unroll
            for (int nd = 0; nd < 4; ++nd)
                vb[nd] = *(const bf16x8*)&Vs[cur][(nd * 16 + l15) * 64 + swz1];
            __builtin_amdgcn_s_setprio(1);
            l_acc = __builtin_amdgcn_mfma_f32_16x16x32_bf16(pa, onesf, l_acc, 0, 0, 0);
            #pragma unroll
            for (int nd = 0; nd < 4; ++nd)
                o_acc[nd] = __builtin_amdgcn_mfma_f32_16x16x32_bf16(pa, vb[nd], o_acc[nd], 0, 0, 0);
            __builtin_amdgcn_s_setprio(0);
        }

        __syncthreads();
    }

    #pragma unroll
    for (int r = 0; r < 4; ++r) {
        float rinv = 1.0f / l_acc[r];
        int row = q0 + w * 16 + quad * 4 + r;
        #pragma unroll
        for (int nd = 0; nd < 4; ++nd)
            Om[((size_t)b * SEQ + row) * HID + h * DKK + nd * 16 + l15] =
                f32_bf16(o_acc[nd][r] * rinv);
    }
}

// ---------------------------------------------------------------------------
// Kernel 3: out = Om @ Wo^T + bo (fp32 out).  128x64 tiles (grid 512 = 2
// blocks/CU), double-buffered single-barrier K-loop.
// ---------------------------------------------------------------------------
__global__ __launch_bounds__(256, 2)
void outproj_kernel(const unsigned short* __restrict__ Om, const unsigned short* __restrict__ Wob,
                    const float* __restrict__ bo_, float* __restrict__ out)
{
    const int m0 = blockIdx.x * 128;
    const int n0 = blockIdx.y * 64;
    const int tid  = threadIdx.x;
    const int lane = tid & 63, wid = tid >> 6;
    const int wm = (wid >> 1) * 64, wn = (wid & 1) * 32;
    const int l15 = lane & 15, quad = lane >> 4;

    __shared__ __align__(16) unsigned short As[2][128 * 32];   // 2 x 8 KB
    __shared__ __align__(16) unsigned short Bs[2][64 * 32];    // 2 x 4 KB

    const int r0 = tid >> 2, cg = tid & 3;
    const unsigned short* gA = Om + (size_t)(m0 + r0) * HID + ((cg ^ (r0 & 3)) * 8);
    const unsigned short* gB = Wob + (size_t)(n0 + r0) * HID + ((cg ^ (r0 & 3)) * 8);
    const int cgsel = (quad ^ (l15 & 3)) * 8;

    f32x4 acc[4][2];
    #pragma unroll
    for (int i = 0; i < 4; ++i)
        #pragma unroll
        for (int j = 0; j < 2; ++j)
            acc[i][j] = f32x4{0.f, 0.f, 0.f, 0.f};

    // prologue: stage k0=0
    glds16(gA, &As[0][tid * 8]);
    glds16(gA + (size_t)64 * HID, &As[0][(tid + 256) * 8]);
    glds16(gB, &Bs[0][tid * 8]);
    __syncthreads();

    for (int k0 = 0; k0 < HID; k0 += 32) {
        const int cur = (k0 >> 5) & 1;
        if (k0 + 32 < HID) {
            const int nb = cur ^ 1;
            glds16(gA + k0 + 32, &As[nb][tid * 8]);
            glds16(gA + (size_t)64 * HID + k0 + 32, &As[nb][(tid + 256) * 8]);
            glds16(gB + k0 + 32, &Bs[nb][tid * 8]);
        }

        bf16x8 af[4], bfr[2];
        #pragma unroll
        for (int mi = 0; mi < 4; ++mi)
            af[mi] = *(const bf16x8*)&As[cur][(wm + mi * 16 + l15) * 32 + cgsel];
        #pragma unroll
        for (int ni = 0; ni < 2; ++ni)
            bfr[ni] = *(const bf16x8*)&Bs[cur][(wn + ni * 16 + l15) * 32 + cgsel];
        __builtin_amdgcn_s_setprio(1);
        #pragma unroll
        for (int mi = 0; mi < 4; ++mi)
            #pragma unroll
            for (int ni = 0; ni < 2; ++ni)
                acc[mi][ni] = __builtin_amdgcn_mfma_f32_16x16x32_bf16(
                    af[mi], bfr[ni], acc[mi][ni], 0, 0, 0);
        __builtin_amdgcn_s_setprio(0);
        __syncthreads();
    }

    #pragma unroll
    for (int mi = 0; mi < 4; ++mi) {
        #pragma unroll
        for (int ni = 0; ni < 2; ++ni) {
            int n = n0 + wn + ni * 16 + l15;
            float bv = bo_[n];
            #pragma unroll
            for (int r = 0; r < 4; ++r) {
                int m = m0 + wm + mi * 16 + quad * 4 + r;
                out[(size_t)m * HID + n] = acc[mi][ni][r] + bv;
            }
        }
    }
}

// ---------------------------------------------------------------------------
extern "C" void kernel_launch(void* const* d_in, const int* in_sizes, int n_in,
                              void* d_out, int out_size, void* d_ws, size_t ws_size,
                              hipStream_t stream) {
    const float* q    = (const float*)d_in[0];
    const float* k    = (const float*)d_in[1];
    const float* v    = (const float*)d_in[2];
    const int*   mask = (const int*)  d_in[3];
    const float* Wq   = (const float*)d_in[4];
    const float* bq   = (const float*)d_in[5];
    const float* Wk   = (const float*)d_in[6];
    const float* bk   = (const float*)d_in[7];
    const float* Wv   = (const float*)d_in[8];
    const float* bv   = (const float*)d_in[9];
    const float* Wo   = (const float*)d_in[10];
    const float* bo   = (const float*)d_in[11];
    float* out = (float*)d_out;

    // workspace layout (bf16 element offsets):
    unsigned short* ws  = (unsigned short*)d_ws;
    unsigned short* qb  = ws;                  // 4194304 elems (B*S*H)
    unsigned short* kbx = ws + 4194304;
    unsigned short* vbx = ws + 8388608;
    unsigned short* Wqb = ws + 12582912;       // 1048576 elems each
    unsigned short* Wkb = ws + 13631488;
    unsigned short* Wvb = ws + 14680064;
    unsigned short* Wob = ws + 15728640;
    unsigned short* Qh  = ws + 16777216;
    unsigned short* Kh  = ws + 20971520;
    unsigned short* Vt  = ws + 25165824;
    unsigned short* Om  = ws;                  // alias qb (dead after proj)
    unsigned long long* Mb = (unsigned long long*)(ws + 29360128);  // 1 MB
    unsigned short* Vh  = (unsigned short*)d_out;  // scratch: out dead until outproj

    prep_kernel<<<dim3(16896), 256, 0, stream>>>(q, k, v, Wq, Wk, Wv, Wo, mask, ws, Mb);

    proj_kernel<<<dim3(32, 8, 3), 256, 0, stream>>>(qb, kbx, vbx, Wqb, Wkb, Wvb,
                                                    bq, bk, bv, Qh, Kh, Vh);
    vtrans_kernel<<<dim3(32, 32), 256, 0, stream>>>(Vh, Vt);
    attn_kernel<<<dim3(32, NHEAD, 2), 256, 0, stream>>>(Qh, Kh, Vt, Mb, Om);
    outproj_kernel<<<dim3(32, 16), 256, 0, stream>>>(Om, Wob, bo, out);
}